// Round 14
// baseline (843.243 us; speedup 1.0000x reference)
//
#include <hip/hip_runtime.h>
#include <stdint.h>

#define MDIM 8192
#define KDIM 4096
#define NDIM 4096
#define MAXFLAGS (2 * 1024 * 1024)

typedef int i32x4 __attribute__((ext_vector_type(4)));

#define VMCNT(n) asm volatile("s_waitcnt vmcnt(" #n ")" ::: "memory")
#define LGKMCNT0 asm volatile("s_waitcnt lgkmcnt(0)" ::: "memory")
#define SB0 __builtin_amdgcn_sched_barrier(0)

__device__ __forceinline__ void gl2lds16(const void* g, void* l) {
  __builtin_amdgcn_global_load_lds(
      (const __attribute__((address_space(1))) void*)(uintptr_t)(g),
      (__attribute__((address_space(3))) void*)(uintptr_t)(l), 16, 0, 0);
}

// ---------------- fused prep: ternarize W0/W1/W2 (transposed) + quantize x + zero cnt ----------------
// grid: [0,12288) tern 64x64 tiles; [12288, 20480) quant blocks (16 floats/thread, 16B stores).
__global__ __launch_bounds__(256) void k_prep(const float* __restrict__ x,
                                              const float* __restrict__ W0,
                                              const float* __restrict__ W1,
                                              const float* __restrict__ W2,
                                              int8_t* __restrict__ Qt0,
                                              int8_t* __restrict__ Qt1,
                                              int8_t* __restrict__ Qt2,
                                              int8_t* __restrict__ dig,
                                              int* __restrict__ cnt) {
  const int bid = blockIdx.x;
  const int tid = threadIdx.x;
  if (bid == 0 && tid == 0) *cnt = 0;
  if (bid < 12288) {
    __shared__ int8_t t[64][68];
    const int wsel = bid >> 12;
    const int r = bid & 4095;
    const int n0 = (r & 63) * 64, k0 = (r >> 6) * 64;
    const float* W = (wsel == 0) ? W0 : (wsel == 1) ? W1 : W2;
    int8_t* Qt = (wsel == 0) ? Qt0 : (wsel == 1) ? Qt1 : Qt2;
    const int c4 = tid & 15, rq = tid >> 4;
#pragma unroll
    for (int i = 0; i < 4; ++i) {
      int row = i * 16 + rq;
      float4 v = *(const float4*)&W[(size_t)(k0 + row) * NDIM + n0 + c4 * 4];
      float f[4] = {v.x, v.y, v.z, v.w};
#pragma unroll
      for (int j = 0; j < 4; ++j) {
        float q = fminf(1.f, fmaxf(-1.f, rintf(f[j])));  // round-half-even = jnp.round
        t[row][c4 * 4 + j] = (int8_t)(int)q;
      }
    }
    __syncthreads();
#pragma unroll
    for (int i = 0; i < 4; ++i) {
      int n = i * 16 + rq;
      char4 o;
      o.x = t[c4 * 4 + 0][n];
      o.y = t[c4 * 4 + 1][n];
      o.z = t[c4 * 4 + 2][n];
      o.w = t[c4 * 4 + 3][n];
      *(char4*)&Qt[(size_t)(n0 + n) * KDIM + k0 + c4 * 4] = o;
    }
  } else {
    // quantize 16 floats/thread to 3 signed base-256 digit planes of round(x * 2^19)
    const size_t P = (size_t)MDIM * KDIM;
    size_t i = ((size_t)(bid - 12288) * 256 + tid) * 16;
    int8_t ob[3][16];
#pragma unroll
    for (int q = 0; q < 4; ++q) {
      float4 v = *(const float4*)(x + i + q * 4);
      float f[4] = {v.x, v.y, v.z, v.w};
#pragma unroll
      for (int j = 0; j < 4; ++j) {
        long long s = __double2ll_rn((double)f[j] * 524288.0);  // exact: f32->f64, *2^19
        int8_t d0 = (int8_t)s; s = (s - d0) >> 8;
        int8_t d1 = (int8_t)s; s = (s - d1) >> 8;
        int8_t d2 = (int8_t)s;  // |x|<8 guaranteed-fit
        ob[0][q * 4 + j] = d0; ob[1][q * 4 + j] = d1; ob[2][q * 4 + j] = d2;
      }
    }
#pragma unroll
    for (int p = 0; p < 3; ++p)
      *(int4*)(dig + p * P + i) = *(const int4*)ob[p];
  }
}

// ---------------- layer 1 (R3-form + column-strip locality): 3 planes x Qt -> sign -> h0 ----------------
// dbuf BK=128, tile 64x128, 8 waves, per-wave 32x32, 80KB LDS -> 2 blocks/CU.
// wg mapping: nb-strip per XCD chunk (B strip 2MB L2-resident; A streams via L3).
__global__ __launch_bounds__(512) void k_gemm_l1(const int8_t* __restrict__ dig,
                                                 const int8_t* __restrict__ Qt,
                                                 int8_t* __restrict__ h,
                                                 int* __restrict__ cnt,
                                                 int2* __restrict__ flags) {
  __shared__ __align__(16) int8_t As[2][3][64][128];  // 48KB
  __shared__ __align__(16) int8_t Bs[2][128][128];    // 32KB
  const int tid = threadIdx.x;
  const int w = tid >> 6, l = tid & 63;
  const size_t P = (size_t)MDIM * KDIM;

  const int nwg = gridDim.x;                                   // 4096, %8==0
  const int wg = (blockIdx.x & 7) * (nwg >> 3) + (blockIdx.x >> 3);
  const int mb = wg & 127, nb = wg >> 7;   // column-strip: each XCD chunk = 4 nb x all mb

  const int srow = tid >> 3;          // 0..63
  const int sswz = (tid & 7) ^ (srow & 7);
  const int8_t* a_src = dig + (size_t)(mb * 64 + srow) * KDIM + sswz * 16;
  const int8_t* b_src0 = Qt + (size_t)(nb * 128 + srow) * KDIM + sswz * 16;
  const int8_t* b_src1 = b_src0 + (size_t)64 * KDIM;

  i32x4 acc[3][2][2];
#pragma unroll
  for (int p = 0; p < 3; ++p)
#pragma unroll
    for (int mi = 0; mi < 2; ++mi)
#pragma unroll
      for (int ni = 0; ni < 2; ++ni) acc[p][mi][ni] = (i32x4){0, 0, 0, 0};

  const int wr = (w >> 2) * 32;
  const int wc = (w & 3) * 32;

  auto stage = [&](int buf, int kk) {
    int8_t* ad = &As[buf][0][0][0] + w * 1024;
    int8_t* bd = &Bs[buf][0][0] + w * 1024;
#pragma unroll
    for (int p = 0; p < 3; ++p) gl2lds16(a_src + p * P + kk, ad + p * 8192);
    gl2lds16(b_src0 + kk, bd);
    gl2lds16(b_src1 + kk, bd + 8192);
  };

  auto compute = [&](int buf) {
#pragma unroll
    for (int ki = 0; ki < 2; ++ki) {
      const int kg = ki * 4 + (l >> 4);
      i32x4 b[2];
#pragma unroll
      for (int ni = 0; ni < 2; ++ni) {
        int nr = wc + ni * 16 + (l & 15);
        b[ni] = *(const i32x4*)&Bs[buf][nr][(kg ^ (nr & 7)) * 16];
      }
      __builtin_amdgcn_s_setprio(1);
#pragma unroll
      for (int p = 0; p < 3; ++p)
#pragma unroll
        for (int mi = 0; mi < 2; ++mi) {
          int ar = wr + mi * 16 + (l & 15);
          i32x4 a = *(const i32x4*)&As[buf][p][ar][(kg ^ (ar & 7)) * 16];
#pragma unroll
          for (int ni = 0; ni < 2; ++ni)
            acc[p][mi][ni] =
                __builtin_amdgcn_mfma_i32_16x16x64_i8(a, b[ni], acc[p][mi][ni], 0, 0, 0);
        }
      __builtin_amdgcn_s_setprio(0);
    }
  };

  // prologue: tiles 0,1 in flight; wait tile0 (allow tile1's 5 loads outstanding)
  stage(0, 0);
  stage(1, 128);
  VMCNT(5);
  SB0;
  __builtin_amdgcn_s_barrier();

  const int NT = KDIM / 128;  // 32
  for (int t = 0; t < NT; ++t) {
    compute(t & 1);
    if (t == NT - 1) break;
    LGKMCNT0; SB0;
    __builtin_amdgcn_s_barrier();               // all waves done reading buf[t&1]
    if (t + 2 < NT) {
      stage(t & 1, (t + 2) * 128);              // overwrite buf[t&1] with tile t+2
      VMCNT(5);                                 // tile t+1 landed; t+2 in flight
    } else {
      VMCNT(0);
    }
    SB0;
    __builtin_amdgcn_s_barrier();               // tile t+1 visible to all
  }

  const int mbase = mb * 64 + wr + ((l >> 4) << 2);
  const int nbase = nb * 128 + wc + (l & 15);
#pragma unroll
  for (int mi = 0; mi < 2; ++mi)
#pragma unroll
    for (int ni = 0; ni < 2; ++ni)
#pragma unroll
      for (int j = 0; j < 4; ++j) {
        int s0 = acc[0][mi][ni][j], s1 = acc[1][mi][ni][j];
        int s2 = acc[2][mi][ni][j];
        double d = ((double)s2 * 256.0 + (double)s1) * 256.0 + (double)s0;
        int sg = (d > 0.0) - (d < 0.0);
        int row = mbase + mi * 16 + j;
        int col = nbase + ni * 16;
        h[(size_t)row * NDIM + col] = (int8_t)sg;
        if (fabs(d) <= 2048.0) {  // certified: |d - 2^19*exact| <= 0.5*4096
          int idx = atomicAdd(cnt, 1);
          if (idx < MAXFLAGS) flags[idx] = make_int2(row, col);
        }
      }
}

// ---------------- exact f64 fixup of flagged (row,col) outputs ----------------
__global__ __launch_bounds__(256) void k_fixup(const float* __restrict__ x,
                                               const int8_t* __restrict__ Qt,
                                               const int* __restrict__ cnt,
                                               const int2* __restrict__ flags,
                                               int8_t* __restrict__ h) {
  __shared__ double red[256];
  int n = *cnt;
  if (n > MAXFLAGS) n = MAXFLAGS;
  for (int i = blockIdx.x; i < n; i += gridDim.x) {
    int2 rc = flags[i];
    const float* xr = x + (size_t)rc.x * KDIM;
    const int8_t* qr = Qt + (size_t)rc.y * KDIM;
    double s = 0.0;
    for (int k = threadIdx.x; k < KDIM; k += 256)
      s += (double)xr[k] * (double)qr[k];
    red[threadIdx.x] = s;
    __syncthreads();
#pragma unroll
    for (int st = 128; st > 0; st >>= 1) {
      if (threadIdx.x < st) red[threadIdx.x] += red[threadIdx.x + st];
      __syncthreads();
    }
    if (threadIdx.x == 0) {
      double d = red[0];
      h[(size_t)rc.x * NDIM + rc.y] = (int8_t)((d > 0.0) - (d < 0.0));
    }
    __syncthreads();
  }
}

// ---------------- layers 2/3 (R9-form + column-strip locality): ring-4 BK=64, tile 256x256 ----------------
template <int F32OUT>
__global__ __launch_bounds__(512, 2) void k_gemm_bin(const int8_t* __restrict__ A,
                                                     const int8_t* __restrict__ Qt,
                                                     void* __restrict__ outp) {
  __shared__ __align__(16) int8_t smem[131072];  // 4 x (A 16KB + B 16KB)
  const int tid = threadIdx.x;
  const int w = tid >> 6, l = tid & 63;

  const int nwg = gridDim.x;                                   // 512, %8==0
  const int wg = (blockIdx.x & 7) * (nwg >> 3) + (blockIdx.x >> 3);
  const int mb = wg & 31, nb = wg >> 5;  // column-strip: each XCD chunk = 2 nb x all mb

  const int srow_in = l >> 2;
  const int scol = (((l & 3) ^ ((l >> 3) & 3)) << 4);
  const int8_t* gA[2];
  const int8_t* gB[2];
#pragma unroll
  for (int s = 0; s < 2; ++s) {
    gA[s] = A + (size_t)(mb * 256 + (2 * w + s) * 16 + srow_in) * KDIM + scol;
    gB[s] = Qt + (size_t)(nb * 256 + (2 * w + s) * 16 + srow_in) * KDIM + scol;
  }

  i32x4 acc[8][4];
#pragma unroll
  for (int mi = 0; mi < 8; ++mi)
#pragma unroll
    for (int ni = 0; ni < 4; ++ni) acc[mi][ni] = (i32x4){0, 0, 0, 0};

  const int wr = (w >> 2) * 128, wc = (w & 3) * 64;
  const int kg = l >> 4;

  auto stage = [&](int buf, int kk) {
    int8_t* sb = smem + buf * 32768;
#pragma unroll
    for (int s = 0; s < 2; ++s) {
      gl2lds16(gA[s] + kk, sb + (2 * w + s) * 1024);
      gl2lds16(gB[s] + kk, sb + 16384 + (2 * w + s) * 1024);
    }
  };

  auto compute = [&](int buf) {
    const int8_t* sb = smem + buf * 32768;
    i32x4 b[4], a[8];
#pragma unroll
    for (int ni = 0; ni < 4; ++ni) {
      int nr = wc + ni * 16 + (l & 15);
      b[ni] = *(const i32x4*)(sb + 16384 + nr * 64 + ((kg ^ ((nr >> 1) & 3)) << 4));
    }
#pragma unroll
    for (int mi = 0; mi < 8; ++mi) {
      int ar = wr + mi * 16 + (l & 15);
      a[mi] = *(const i32x4*)(sb + ar * 64 + ((kg ^ ((ar >> 1) & 3)) << 4));
    }
    __builtin_amdgcn_s_setprio(1);
#pragma unroll
    for (int mi = 0; mi < 8; ++mi)
#pragma unroll
      for (int ni = 0; ni < 4; ++ni)
        acc[mi][ni] =
            __builtin_amdgcn_mfma_i32_16x16x64_i8(a[mi], b[ni], acc[mi][ni], 0, 0, 0);
    __builtin_amdgcn_s_setprio(0);
  };

  const int NT = KDIM / 64;  // 64
  stage(0, 0); stage(1, 64); stage(2, 128);
  VMCNT(8);
  SB0;
  __builtin_amdgcn_s_barrier();

  for (int t = 0; t < NT; ++t) {
    if (t + 3 < NT) stage((t + 3) & 3, (t + 3) * 64);
    SB0;
    compute(t & 3);
    if (t == NT - 1) break;
    LGKMCNT0;
    if (t + 3 < NT) {
      VMCNT(8);
    } else if (t + 2 < NT) {
      VMCNT(4);
    } else {
      VMCNT(0);
    }
    SB0;
    __builtin_amdgcn_s_barrier();
  }

  const int mbase = mb * 256 + wr + ((l >> 4) << 2);
  const int nbase = nb * 256 + wc + (l & 15);
#pragma unroll
  for (int mi = 0; mi < 8; ++mi)
#pragma unroll
    for (int ni = 0; ni < 4; ++ni)
#pragma unroll
      for (int j = 0; j < 4; ++j) {
        int s = acc[mi][ni][j];
        int sg = (s > 0) - (s < 0);
        size_t off = (size_t)(mbase + mi * 16 + j) * NDIM + (nbase + ni * 16);
        if (F32OUT)
          ((float*)outp)[off] = (float)sg;
        else
          ((int8_t*)outp)[off] = (int8_t)sg;
      }
}

extern "C" void kernel_launch(void* const* d_in, const int* in_sizes, int n_in,
                              void* d_out, int out_size, void* d_ws, size_t ws_size,
                              hipStream_t stream) {
  (void)in_sizes; (void)n_in; (void)out_size; (void)ws_size;
  const float* x  = (const float*)d_in[0];
  const float* W0 = (const float*)d_in[1];
  const float* W1 = (const float*)d_in[2];
  const float* W2 = (const float*)d_in[3];
  float* out = (float*)d_out;

  const size_t QB = (size_t)KDIM * NDIM;   // 16.78 MB each
  const size_t HB = (size_t)MDIM * NDIM;   // 33.55 MB each
  int8_t* Qt0 = (int8_t*)d_ws;
  int8_t* Qt1 = Qt0 + QB;
  int8_t* Qt2 = Qt1 + QB;
  int8_t* h0  = Qt2 + QB;
  int8_t* h1  = h0 + HB;                   // ws total: 117.4 MB

  int8_t* dig = (int8_t*)d_out;            // 3 planes = 100.7 MB
  int2* flags = (int2*)((char*)d_out + 3 * HB);
  int* cnt = (int*)((char*)d_out + 3 * HB + (size_t)MAXFLAGS * 8);

  k_prep<<<20480, 256, 0, stream>>>(x, W0, W1, W2, Qt0, Qt1, Qt2, dig, cnt);
  k_gemm_l1<<<(MDIM / 64) * (NDIM / 128), 512, 0, stream>>>(dig, Qt0, h0, cnt, flags);
  k_fixup<<<512, 256, 0, stream>>>(x, Qt0, cnt, flags, h0);
  k_gemm_bin<0><<<(MDIM / 256) * (NDIM / 256), 512, 0, stream>>>(h0, Qt1, h1);
  k_gemm_bin<1><<<(MDIM / 256) * (NDIM / 256), 512, 0, stream>>>(h1, Qt2, out);
}

// Round 15
// 734.164 us; speedup vs baseline: 1.1486x; 1.1486x over previous
//
#include <hip/hip_runtime.h>
#include <stdint.h>

#define MDIM 8192
#define KDIM 4096
#define NDIM 4096
#define MAXFLAGS (2 * 1024 * 1024)

typedef int i32x4 __attribute__((ext_vector_type(4)));

#define VMCNT(n) asm volatile("s_waitcnt vmcnt(" #n ")" ::: "memory")
#define LGKMCNT0 asm volatile("s_waitcnt lgkmcnt(0)" ::: "memory")
#define SB0 __builtin_amdgcn_sched_barrier(0)

__device__ __forceinline__ void gl2lds16(const void* g, void* l) {
  __builtin_amdgcn_global_load_lds(
      (const __attribute__((address_space(1))) void*)(uintptr_t)(g),
      (__attribute__((address_space(3))) void*)(uintptr_t)(l), 16, 0, 0);
}

// ---------------- fused prep: ternarize W0/W1/W2 (transposed) + quantize x + zero cnt ----------------
// grid: [0,12288) tern 64x64 tiles; [12288, 20480) quant blocks (16 floats/thread, 16B stores).
__global__ __launch_bounds__(256) void k_prep(const float* __restrict__ x,
                                              const float* __restrict__ W0,
                                              const float* __restrict__ W1,
                                              const float* __restrict__ W2,
                                              int8_t* __restrict__ Qt0,
                                              int8_t* __restrict__ Qt1,
                                              int8_t* __restrict__ Qt2,
                                              int8_t* __restrict__ dig,
                                              int* __restrict__ cnt) {
  const int bid = blockIdx.x;
  const int tid = threadIdx.x;
  if (bid == 0 && tid == 0) *cnt = 0;
  if (bid < 12288) {
    __shared__ int8_t t[64][68];
    const int wsel = bid >> 12;
    const int r = bid & 4095;
    const int n0 = (r & 63) * 64, k0 = (r >> 6) * 64;
    const float* W = (wsel == 0) ? W0 : (wsel == 1) ? W1 : W2;
    int8_t* Qt = (wsel == 0) ? Qt0 : (wsel == 1) ? Qt1 : Qt2;
    const int c4 = tid & 15, rq = tid >> 4;
#pragma unroll
    for (int i = 0; i < 4; ++i) {
      int row = i * 16 + rq;
      float4 v = *(const float4*)&W[(size_t)(k0 + row) * NDIM + n0 + c4 * 4];
      float f[4] = {v.x, v.y, v.z, v.w};
#pragma unroll
      for (int j = 0; j < 4; ++j) {
        float q = fminf(1.f, fmaxf(-1.f, rintf(f[j])));  // round-half-even = jnp.round
        t[row][c4 * 4 + j] = (int8_t)(int)q;
      }
    }
    __syncthreads();
#pragma unroll
    for (int i = 0; i < 4; ++i) {
      int n = i * 16 + rq;
      char4 o;
      o.x = t[c4 * 4 + 0][n];
      o.y = t[c4 * 4 + 1][n];
      o.z = t[c4 * 4 + 2][n];
      o.w = t[c4 * 4 + 3][n];
      *(char4*)&Qt[(size_t)(n0 + n) * KDIM + k0 + c4 * 4] = o;
    }
  } else {
    // quantize 16 floats/thread to 3 signed base-256 digit planes of round(x * 2^19)
    const size_t P = (size_t)MDIM * KDIM;
    size_t i = ((size_t)(bid - 12288) * 256 + tid) * 16;
    int8_t ob[3][16];
#pragma unroll
    for (int q = 0; q < 4; ++q) {
      float4 v = *(const float4*)(x + i + q * 4);
      float f[4] = {v.x, v.y, v.z, v.w};
#pragma unroll
      for (int j = 0; j < 4; ++j) {
        long long s = __double2ll_rn((double)f[j] * 524288.0);  // exact: f32->f64, *2^19
        int8_t d0 = (int8_t)s; s = (s - d0) >> 8;
        int8_t d1 = (int8_t)s; s = (s - d1) >> 8;
        int8_t d2 = (int8_t)s;  // |x|<8 guaranteed-fit
        ob[0][q * 4 + j] = d0; ob[1][q * 4 + j] = d1; ob[2][q * 4 + j] = d2;
      }
    }
#pragma unroll
    for (int p = 0; p < 3; ++p)
      *(int4*)(dig + p * P + i) = *(const int4*)ob[p];
  }
}

// ---------------- layer 1 (R3-form, proven 5x): 3 planes x Qt -> sign -> h0, flag |sum|<=2048 ----------------
// dbuf BK=128, tile 64x128, 8 waves, per-wave 32x32, 80KB LDS -> 2 blocks/CU.
// nb-minor wg mapping: resident window = ~2 mb-panels -> A-window L2-resident (R14 lesson).
__global__ __launch_bounds__(512) void k_gemm_l1(const int8_t* __restrict__ dig,
                                                 const int8_t* __restrict__ Qt,
                                                 int8_t* __restrict__ h,
                                                 int* __restrict__ cnt,
                                                 int2* __restrict__ flags) {
  __shared__ __align__(16) int8_t As[2][3][64][128];  // 48KB
  __shared__ __align__(16) int8_t Bs[2][128][128];    // 32KB
  const int tid = threadIdx.x;
  const int w = tid >> 6, l = tid & 63;
  const size_t P = (size_t)MDIM * KDIM;

  const int nwg = gridDim.x;                                   // 4096, %8==0
  const int wg = (blockIdx.x & 7) * (nwg >> 3) + (blockIdx.x >> 3);
  const int NB = NDIM / 128;                                   // 32
  const int mb = wg / NB, nb = wg % NB;

  const int srow = tid >> 3;          // 0..63
  const int sswz = (tid & 7) ^ (srow & 7);
  const int8_t* a_src = dig + (size_t)(mb * 64 + srow) * KDIM + sswz * 16;
  const int8_t* b_src0 = Qt + (size_t)(nb * 128 + srow) * KDIM + sswz * 16;
  const int8_t* b_src1 = b_src0 + (size_t)64 * KDIM;

  i32x4 acc[3][2][2];
#pragma unroll
  for (int p = 0; p < 3; ++p)
#pragma unroll
    for (int mi = 0; mi < 2; ++mi)
#pragma unroll
      for (int ni = 0; ni < 2; ++ni) acc[p][mi][ni] = (i32x4){0, 0, 0, 0};

  const int wr = (w >> 2) * 32;
  const int wc = (w & 3) * 32;

  auto stage = [&](int buf, int kk) {
    int8_t* ad = &As[buf][0][0][0] + w * 1024;
    int8_t* bd = &Bs[buf][0][0] + w * 1024;
#pragma unroll
    for (int p = 0; p < 3; ++p) gl2lds16(a_src + p * P + kk, ad + p * 8192);
    gl2lds16(b_src0 + kk, bd);
    gl2lds16(b_src1 + kk, bd + 8192);
  };

  auto compute = [&](int buf) {
#pragma unroll
    for (int ki = 0; ki < 2; ++ki) {
      const int kg = ki * 4 + (l >> 4);
      i32x4 b[2];
#pragma unroll
      for (int ni = 0; ni < 2; ++ni) {
        int nr = wc + ni * 16 + (l & 15);
        b[ni] = *(const i32x4*)&Bs[buf][nr][(kg ^ (nr & 7)) * 16];
      }
      __builtin_amdgcn_s_setprio(1);
#pragma unroll
      for (int p = 0; p < 3; ++p)
#pragma unroll
        for (int mi = 0; mi < 2; ++mi) {
          int ar = wr + mi * 16 + (l & 15);
          i32x4 a = *(const i32x4*)&As[buf][p][ar][(kg ^ (ar & 7)) * 16];
#pragma unroll
          for (int ni = 0; ni < 2; ++ni)
            acc[p][mi][ni] =
                __builtin_amdgcn_mfma_i32_16x16x64_i8(a, b[ni], acc[p][mi][ni], 0, 0, 0);
        }
      __builtin_amdgcn_s_setprio(0);
    }
  };

  // prologue: tiles 0,1 in flight; wait tile0 (allow tile1's 5 loads outstanding)
  stage(0, 0);
  stage(1, 128);
  VMCNT(5);
  SB0;
  __builtin_amdgcn_s_barrier();

  const int NT = KDIM / 128;  // 32
  for (int t = 0; t < NT; ++t) {
    compute(t & 1);
    if (t == NT - 1) break;
    LGKMCNT0; SB0;
    __builtin_amdgcn_s_barrier();               // all waves done reading buf[t&1]
    if (t + 2 < NT) {
      stage(t & 1, (t + 2) * 128);              // overwrite buf[t&1] with tile t+2
      VMCNT(5);                                 // tile t+1 landed; t+2 in flight
    } else {
      VMCNT(0);
    }
    SB0;
    __builtin_amdgcn_s_barrier();               // tile t+1 visible to all
  }

  const int mbase = mb * 64 + wr + ((l >> 4) << 2);
  const int nbase = nb * 128 + wc + (l & 15);
#pragma unroll
  for (int mi = 0; mi < 2; ++mi)
#pragma unroll
    for (int ni = 0; ni < 2; ++ni)
#pragma unroll
      for (int j = 0; j < 4; ++j) {
        int s0 = acc[0][mi][ni][j], s1 = acc[1][mi][ni][j];
        int s2 = acc[2][mi][ni][j];
        double d = ((double)s2 * 256.0 + (double)s1) * 256.0 + (double)s0;
        int sg = (d > 0.0) - (d < 0.0);
        int row = mbase + mi * 16 + j;
        int col = nbase + ni * 16;
        h[(size_t)row * NDIM + col] = (int8_t)sg;
        if (fabs(d) <= 2048.0) {  // certified: |d - 2^19*exact| <= 0.5*4096
          int idx = atomicAdd(cnt, 1);
          if (idx < MAXFLAGS) flags[idx] = make_int2(row, col);
        }
      }
}

// ---------------- exact f64 fixup of flagged (row,col) outputs ----------------
__global__ __launch_bounds__(256) void k_fixup(const float* __restrict__ x,
                                               const int8_t* __restrict__ Qt,
                                               const int* __restrict__ cnt,
                                               const int2* __restrict__ flags,
                                               int8_t* __restrict__ h) {
  __shared__ double red[256];
  int n = *cnt;
  if (n > MAXFLAGS) n = MAXFLAGS;
  for (int i = blockIdx.x; i < n; i += gridDim.x) {
    int2 rc = flags[i];
    const float* xr = x + (size_t)rc.x * KDIM;
    const int8_t* qr = Qt + (size_t)rc.y * KDIM;
    double s = 0.0;
    for (int k = threadIdx.x; k < KDIM; k += 256)
      s += (double)xr[k] * (double)qr[k];
    red[threadIdx.x] = s;
    __syncthreads();
#pragma unroll
    for (int st = 128; st > 0; st >>= 1) {
      if (threadIdx.x < st) red[threadIdx.x] += red[threadIdx.x + st];
      __syncthreads();
    }
    if (threadIdx.x == 0) {
      double d = red[0];
      h[(size_t)rc.x * NDIM + rc.y] = (int8_t)((d > 0.0) - (d < 0.0));
    }
    __syncthreads();
  }
}

// ---------------- layers 2/3 (R9-proven, 76% util): ring-4 BK=64 issue-early, tile 256x256 ----------------
template <int F32OUT>
__global__ __launch_bounds__(512, 2) void k_gemm_bin(const int8_t* __restrict__ A,
                                                     const int8_t* __restrict__ Qt,
                                                     void* __restrict__ outp) {
  __shared__ __align__(16) int8_t smem[131072];  // 4 x (A 16KB + B 16KB)
  const int tid = threadIdx.x;
  const int w = tid >> 6, l = tid & 63;

  const int nwg = gridDim.x;                                   // 512, %8==0
  const int wg = (blockIdx.x & 7) * (nwg >> 3) + (blockIdx.x >> 3);
  const int NB = NDIM / 256;                                   // 16
  const int mb = wg / NB, nb = wg % NB;

  const int srow_in = l >> 2;
  const int scol = (((l & 3) ^ ((l >> 3) & 3)) << 4);
  const int8_t* gA[2];
  const int8_t* gB[2];
#pragma unroll
  for (int s = 0; s < 2; ++s) {
    gA[s] = A + (size_t)(mb * 256 + (2 * w + s) * 16 + srow_in) * KDIM + scol;
    gB[s] = Qt + (size_t)(nb * 256 + (2 * w + s) * 16 + srow_in) * KDIM + scol;
  }

  i32x4 acc[8][4];
#pragma unroll
  for (int mi = 0; mi < 8; ++mi)
#pragma unroll
    for (int ni = 0; ni < 4; ++ni) acc[mi][ni] = (i32x4){0, 0, 0, 0};

  const int wr = (w >> 2) * 128, wc = (w & 3) * 64;
  const int kg = l >> 4;

  auto stage = [&](int buf, int kk) {
    int8_t* sb = smem + buf * 32768;
#pragma unroll
    for (int s = 0; s < 2; ++s) {
      gl2lds16(gA[s] + kk, sb + (2 * w + s) * 1024);
      gl2lds16(gB[s] + kk, sb + 16384 + (2 * w + s) * 1024);
    }
  };

  auto compute = [&](int buf) {
    const int8_t* sb = smem + buf * 32768;
    i32x4 b[4], a[8];
#pragma unroll
    for (int ni = 0; ni < 4; ++ni) {
      int nr = wc + ni * 16 + (l & 15);
      b[ni] = *(const i32x4*)(sb + 16384 + nr * 64 + ((kg ^ ((nr >> 1) & 3)) << 4));
    }
#pragma unroll
    for (int mi = 0; mi < 8; ++mi) {
      int ar = wr + mi * 16 + (l & 15);
      a[mi] = *(const i32x4*)(sb + ar * 64 + ((kg ^ ((ar >> 1) & 3)) << 4));
    }
    __builtin_amdgcn_s_setprio(1);
#pragma unroll
    for (int mi = 0; mi < 8; ++mi)
#pragma unroll
      for (int ni = 0; ni < 4; ++ni)
        acc[mi][ni] =
            __builtin_amdgcn_mfma_i32_16x16x64_i8(a[mi], b[ni], acc[mi][ni], 0, 0, 0);
    __builtin_amdgcn_s_setprio(0);
  };

  const int NT = KDIM / 64;  // 64
  stage(0, 0); stage(1, 64); stage(2, 128);
  VMCNT(8);
  SB0;
  __builtin_amdgcn_s_barrier();

  for (int t = 0; t < NT; ++t) {
    if (t + 3 < NT) stage((t + 3) & 3, (t + 3) * 64);
    SB0;
    compute(t & 3);
    if (t == NT - 1) break;
    LGKMCNT0;
    if (t + 3 < NT) {
      VMCNT(8);
    } else if (t + 2 < NT) {
      VMCNT(4);
    } else {
      VMCNT(0);
    }
    SB0;
    __builtin_amdgcn_s_barrier();
  }

  const int mbase = mb * 256 + wr + ((l >> 4) << 2);
  const int nbase = nb * 256 + wc + (l & 15);
#pragma unroll
  for (int mi = 0; mi < 8; ++mi)
#pragma unroll
    for (int ni = 0; ni < 4; ++ni)
#pragma unroll
      for (int j = 0; j < 4; ++j) {
        int s = acc[mi][ni][j];
        int sg = (s > 0) - (s < 0);
        size_t off = (size_t)(mbase + mi * 16 + j) * NDIM + (nbase + ni * 16);
        if (F32OUT)
          ((float*)outp)[off] = (float)sg;
        else
          ((int8_t*)outp)[off] = (int8_t)sg;
      }
}

extern "C" void kernel_launch(void* const* d_in, const int* in_sizes, int n_in,
                              void* d_out, int out_size, void* d_ws, size_t ws_size,
                              hipStream_t stream) {
  (void)in_sizes; (void)n_in; (void)out_size; (void)ws_size;
  const float* x  = (const float*)d_in[0];
  const float* W0 = (const float*)d_in[1];
  const float* W1 = (const float*)d_in[2];
  const float* W2 = (const float*)d_in[3];
  float* out = (float*)d_out;

  const size_t QB = (size_t)KDIM * NDIM;   // 16.78 MB each
  const size_t HB = (size_t)MDIM * NDIM;   // 33.55 MB each
  int8_t* Qt0 = (int8_t*)d_ws;
  int8_t* Qt1 = Qt0 + QB;
  int8_t* Qt2 = Qt1 + QB;
  int8_t* h0  = Qt2 + QB;
  int8_t* h1  = h0 + HB;                   // ws total: 117.4 MB

  int8_t* dig = (int8_t*)d_out;            // 3 planes = 100.7 MB
  int2* flags = (int2*)((char*)d_out + 3 * HB);
  int* cnt = (int*)((char*)d_out + 3 * HB + (size_t)MAXFLAGS * 8);

  k_prep<<<20480, 256, 0, stream>>>(x, W0, W1, W2, Qt0, Qt1, Qt2, dig, cnt);
  k_gemm_l1<<<(MDIM / 64) * (NDIM / 128), 512, 0, stream>>>(dig, Qt0, h0, cnt, flags);
  k_fixup<<<512, 256, 0, stream>>>(x, Qt0, cnt, flags, h0);
  k_gemm_bin<0><<<(MDIM / 256) * (NDIM / 256), 512, 0, stream>>>(h0, Qt1, h1);
  k_gemm_bin<1><<<(MDIM / 256) * (NDIM / 256), 512, 0, stream>>>(h1, Qt2, out);
}